// Round 1
// baseline (397.174 us; speedup 1.0000x reference)
//
#include <hip/hip_runtime.h>

#define TV 32
#define TT 8192
#define TL 16
#define NCHAIN (TV * TL)        // 512 chains
#define CHUNK 128
#define WARM 128
#define NCHUNK (TT / CHUNK)     // 64
#define JIT 1e-6f
#define C_LOG2PI 1.837877066409345483560659472811f

// ---------------------------------------------------------------------------
// Forward Kalman filter, chunked over time with warm-up.
// One thread per (chunk, chain). Warm-up starts from the exact stationary
// prior (m=0, P=P0); filter forgets init at ~0.9x/step so 128 warm-up steps
// leave ~1e-6 error. Chunk 0 is exact (u0 == 0 == reference init).
// ---------------------------------------------------------------------------
__global__ __launch_bounds__(64) void kf_fwd(
    const float* __restrict__ dt,    // (V, T-1)
    const float* __restrict__ y,     // (V, T, L)
    const float* __restrict__ rvar,  // (V, T, L)
    const float* __restrict__ ls,    // (L)
    const float* __restrict__ var,   // (L)
    float* __restrict__ m_fs,        // (V,L,T,2)
    float* __restrict__ P_fs,        // (V,L,T,4)
    float* __restrict__ slp)         // (V) -- pre-zeroed, atomicAdd
{
    const int tid   = blockIdx.x * 64 + threadIdx.x;
    const int chain = tid & (NCHAIN - 1);   // consecutive lanes = consecutive chains
    const int chunk = tid / NCHAIN;
    const int v = chain >> 4;
    const int l = chain & 15;

    const float lam = 1.7320508075688772f / ls[l];   // sqrt(3)/lengthscale
    const float v0  = var[l];
    const float v1  = v0 * lam * lam;

    const int s  = chunk * CHUNK;
    const int e  = s + CHUNK;
    const int u0 = (s >= WARM) ? (s - WARM) : 0;

    const float* dtv = dt + (size_t)v * (TT - 1);
    const float* yp  = y    + (size_t)v * TT * TL + l;
    const float* rp  = rvar + (size_t)v * TT * TL + l;
    float2* mo = (float2*)(m_fs + (size_t)chain * TT * 2);
    float4* Po = (float4*)(P_fs + (size_t)chain * TT * 4);

    float m0 = 0.f, m1 = 0.f;
    float P00 = v0, P01 = 0.f, P10 = 0.f, P11 = v1;
    float acc = 0.f;

    for (int t = u0; t < e; ++t) {
        // transition from dt_f[t] = (t==0 ? 0 : dt[t-1]); exact A=I,Q=0 at t=0
        const float dtc = (t == 0) ? 0.f : dtv[t - 1];
        const float ldt = dtc * lam;
        const float ee  = __expf(-ldt);
        const float a11 = ee * (ldt + 1.f);
        const float a12 = ee * dtc;
        const float a21 = -ee * lam * ldt;
        const float a22 = ee * (1.f - ldt);
        // Q = P0 - A P0 A^T  (P0 = diag(v0, v1))
        const float q00 = v0 - (a11 * a11 * v0 + a12 * a12 * v1);
        const float q01 = -(a11 * a21 * v0 + a12 * a22 * v1);
        const float q11 = v1 - (a21 * a21 * v0 + a22 * a22 * v1);

        const float yv = yp[(size_t)t * TL];
        const float rv = rp[(size_t)t * TL];

        // predict
        const float mp0 = a11 * m0 + a12 * m1;
        const float mp1 = a21 * m0 + a22 * m1;
        const float ap00 = a11 * P00 + a12 * P10;
        const float ap01 = a11 * P01 + a12 * P11;
        const float ap10 = a21 * P00 + a22 * P10;
        const float ap11 = a21 * P01 + a22 * P11;
        const float pp00 = ap00 * a11 + ap01 * a12 + q00;
        const float pp01 = ap00 * a21 + ap01 * a22 + q01;
        const float pp10 = ap10 * a11 + ap11 * a12 + q01;
        const float pp11 = ap10 * a21 + ap11 * a22 + q11;

        // update (H = [1,0])
        const float ssv  = pp00 + rv;
        const float d    = yv - mp0;
        const float sinv = __builtin_amdgcn_rcpf(ssv + JIT);
        const float W0 = pp00 * sinv;
        const float W1 = pp01 * sinv;
        m0 = mp0 + W0 * d;
        m1 = mp1 + W1 * d;
        P00 = pp00 - W0 * pp00;
        P01 = pp01 - W0 * pp01;
        P10 = pp10 - W1 * pp00;
        P11 = pp11 - W1 * pp01;

        if (t >= s) {   // uniform across wave: no divergence
            acc += -0.5f * (d * d / ssv + __logf(ssv) + C_LOG2PI);
            mo[t] = make_float2(m0, m1);
            Po[t] = make_float4(P00, P01, P10, P11);
        }
    }

    // reduce log_p over the 16 l-lanes sharing this v, then one atomic
    for (int mask = 8; mask >= 1; mask >>= 1)
        acc += __shfl_xor(acc, mask, 16);
    if ((threadIdx.x & 15) == 0)
        atomicAdd(&slp[v], acc);
}

// ---------------------------------------------------------------------------
// Backward RTS smoother, chunked with warm-up from the right. Carry is
// initialized to the filtered state at t0 (EXACT at t0 == T-1, since
// dt_s[T-1]=0 => A=I, Q=0 => smoothed == filtered there per reference).
// ---------------------------------------------------------------------------
__global__ __launch_bounds__(64) void kf_bwd(
    const float* __restrict__ dt,
    const float* __restrict__ ls,
    const float* __restrict__ var,
    const float* __restrict__ m_fs,
    const float* __restrict__ P_fs,
    float* __restrict__ mZ,   // (V,L,T)
    float* __restrict__ PZ)   // (V,L,T)
{
    const int tid   = blockIdx.x * 64 + threadIdx.x;
    const int chain = tid & (NCHAIN - 1);
    const int chunk = tid / NCHAIN;
    const int v = chain >> 4;
    const int l = chain & 15;

    const float lam = 1.7320508075688772f / ls[l];
    const float v0  = var[l];
    const float v1  = v0 * lam * lam;

    const int s = chunk * CHUNK;
    const int e = s + CHUNK;
    int t0 = e - 1 + WARM;
    if (t0 > TT - 1) t0 = TT - 1;

    const float* dtv = dt + (size_t)v * (TT - 1);
    const float2* mi = (const float2*)(m_fs + (size_t)chain * TT * 2);
    const float4* Pi = (const float4*)(P_fs + (size_t)chain * TT * 4);
    float* mo = mZ + (size_t)chain * TT;
    float* Po = PZ + (size_t)chain * TT;

    float2 mf2 = mi[t0];
    float4 Pf4 = Pi[t0];
    float ms0 = mf2.x, ms1 = mf2.y;
    float Ps00 = Pf4.x, Ps01 = Pf4.y, Ps10 = Pf4.z, Ps11 = Pf4.w;
    if (t0 < e) { mo[t0] = ms0; Po[t0] = Ps00; }   // only last chunk (t0==T-1)

    for (int t = t0 - 1; t >= s; --t) {
        // A_s[t], Q_s[t] from dt_s[t] = dt[t]  (t <= T-2 always here)
        const float dtc = dtv[t];
        const float ldt = dtc * lam;
        const float ee  = __expf(-ldt);
        const float a11 = ee * (ldt + 1.f);
        const float a12 = ee * dtc;
        const float a21 = -ee * lam * ldt;
        const float a22 = ee * (1.f - ldt);
        const float q00 = v0 - (a11 * a11 * v0 + a12 * a12 * v1);
        const float q01 = -(a11 * a21 * v0 + a12 * a22 * v1);
        const float q11 = v1 - (a21 * a21 * v0 + a22 * a22 * v1);

        mf2 = mi[t];
        Pf4 = Pi[t];
        const float mf0 = mf2.x, mf1 = mf2.y;
        const float Pf00 = Pf4.x, Pf01 = Pf4.y, Pf10 = Pf4.z, Pf11 = Pf4.w;

        const float mp0 = a11 * mf0 + a12 * mf1;
        const float mp1 = a21 * mf0 + a22 * mf1;
        const float ap00 = a11 * Pf00 + a12 * Pf10;   // A_Pf = A @ P_f
        const float ap01 = a11 * Pf01 + a12 * Pf11;
        const float ap10 = a21 * Pf00 + a22 * Pf10;
        const float ap11 = a21 * Pf01 + a22 * Pf11;
        const float pp00 = ap00 * a11 + ap01 * a12 + q00;
        const float pp01 = ap00 * a21 + ap01 * a22 + q01;
        const float pp10 = ap10 * a11 + ap11 * a12 + q01;
        const float pp11 = ap10 * a21 + ap11 * a22 + q11;

        // G = (solve(P_p + jI, A_Pf))^T  via 2x2 adjugate
        const float M00 = pp00 + JIT, M01 = pp01, M10 = pp10, M11 = pp11 + JIT;
        const float dinv = __builtin_amdgcn_rcpf(M00 * M11 - M01 * M10);
        const float G00 = (M11 * ap00 - M01 * ap10) * dinv;   // X00
        const float G01 = (-M10 * ap00 + M00 * ap10) * dinv;  // X10
        const float G10 = (M11 * ap01 - M01 * ap11) * dinv;   // X01
        const float G11 = (-M10 * ap01 + M00 * ap11) * dinv;  // X11

        // m_s = m_f + G (m_s - m_p)
        const float dm0 = ms0 - mp0, dm1 = ms1 - mp1;
        const float nms0 = mf0 + G00 * dm0 + G01 * dm1;
        const float nms1 = mf1 + G10 * dm0 + G11 * dm1;
        // P_s = P_f - G (P_s - P_p) G^T
        const float D00 = Ps00 - pp00, D01 = Ps01 - pp01;
        const float D10 = Ps10 - pp10, D11 = Ps11 - pp11;
        const float gd00 = G00 * D00 + G01 * D10;
        const float gd01 = G00 * D01 + G01 * D11;
        const float gd10 = G10 * D00 + G11 * D10;
        const float gd11 = G10 * D01 + G11 * D11;
        ms0 = nms0; ms1 = nms1;
        Ps00 = Pf00 - (gd00 * G00 + gd01 * G01);
        Ps01 = Pf01 - (gd00 * G10 + gd01 * G11);
        Ps10 = Pf10 - (gd10 * G00 + gd11 * G01);
        Ps11 = Pf11 - (gd10 * G10 + gd11 * G11);

        if (t < e) { mo[t] = ms0; Po[t] = Ps00; }
    }
}

extern "C" void kernel_launch(void* const* d_in, const int* in_sizes, int n_in,
                              void* d_out, int out_size, void* d_ws, size_t ws_size,
                              hipStream_t stream) {
    const float* dt  = (const float*)d_in[0];
    const float* y   = (const float*)d_in[1];
    const float* rv  = (const float*)d_in[2];
    const float* ls  = (const float*)d_in[3];
    const float* var = (const float*)d_in[4];

    float* out  = (float*)d_out;
    float* m_fs = out;                                    // V*L*T*2
    float* P_fs = m_fs + (size_t)NCHAIN * TT * 2;         // V*L*T*4
    float* mZ   = P_fs + (size_t)NCHAIN * TT * 4;         // V*L*T
    float* PZ   = mZ + (size_t)NCHAIN * TT;               // V*L*T
    float* slp  = PZ + (size_t)NCHAIN * TT;               // V

    hipMemsetAsync(slp, 0, TV * sizeof(float), stream);   // graph-capture safe

    const int ntask = NCHAIN * NCHUNK;                    // 32768 threads
    kf_fwd<<<ntask / 64, 64, 0, stream>>>(dt, y, rv, ls, var, m_fs, P_fs, slp);
    kf_bwd<<<ntask / 64, 64, 0, stream>>>(dt, ls, var, m_fs, P_fs, mZ, PZ);
}

// Round 2
// 391.569 us; speedup vs baseline: 1.0143x; 1.0143x over previous
//
#include <hip/hip_runtime.h>

#define TV 32
#define TT 8192
#define TL 16
#define NCHAIN (TV * TL)        // 512 chains
#define CHUNK 32
#define WARM 128
#define NCHUNK (TT / CHUNK)     // 256
#define BATCH 8
#define JIT 1e-6f
#define C_LOG2PI 1.837877066409345483560659472811f

// ---------------------------------------------------------------------------
// Forward Kalman filter, chunked over time with warm-up.
// One thread per (chunk, chain). Warm-up starts from the exact stationary
// prior (m=0, P=P0); the filter forgets its init at ~e^{-lam dt}(1-W) per
// step => ~1e-3..1e-4 residual after 128 steps. Chunk 0 is exact.
// 8-step register batching keeps ~24 loads in flight per wave (MLP).
// ---------------------------------------------------------------------------
__global__ __launch_bounds__(256) void kf_fwd(
    const float* __restrict__ dt,    // (V, T-1)
    const float* __restrict__ y,     // (V, T, L)
    const float* __restrict__ rvar,  // (V, T, L)
    const float* __restrict__ ls,    // (L)
    const float* __restrict__ var,   // (L)
    float* __restrict__ m_fs,        // (V,L,T,2)
    float* __restrict__ P_fs,        // (V,L,T,4)
    float* __restrict__ slp)         // (V) -- pre-zeroed, atomicAdd
{
    const int tid   = blockIdx.x * 256 + threadIdx.x;
    const int chain = tid & (NCHAIN - 1);   // consecutive lanes = consecutive chains
    const int chunk = tid / NCHAIN;
    const int v = chain >> 4;
    const int l = chain & 15;

    const float lam = 1.7320508075688772f / ls[l];   // sqrt(3)/lengthscale
    const float v0  = var[l];
    const float v1  = v0 * lam * lam;

    const int s  = chunk * CHUNK;
    const int e  = s + CHUNK;
    const int u0 = (s >= WARM) ? (s - WARM) : 0;

    const float* dtv = dt + (size_t)v * (TT - 1);
    const float* yp  = y    + (size_t)v * TT * TL + l;
    const float* rp  = rvar + (size_t)v * TT * TL + l;
    float2* mo = (float2*)(m_fs + (size_t)chain * TT * 2);
    float4* Po = (float4*)(P_fs + (size_t)chain * TT * 4);

    float m0 = 0.f, m1 = 0.f;
    float P00 = v0, P01 = 0.f, P10 = 0.f, P11 = v1;
    float acc = 0.f;

    // u0, s, e are multiples of 32 => groups of BATCH never straddle s.
    for (int t = u0; t < e; t += BATCH) {
        float yb[BATCH], rb[BATCH], db[BATCH];
#pragma unroll
        for (int j = 0; j < BATCH; ++j) {
            const int tt = t + j;
            yb[j] = yp[(size_t)tt * TL];
            rb[j] = rp[(size_t)tt * TL];
            db[j] = dtv[(tt >= 1) ? (tt - 1) : 0];
        }
#pragma unroll
        for (int j = 0; j < BATCH; ++j) {
            const int tt = t + j;
            const float dtc = (tt == 0) ? 0.f : db[j];   // exact A=I,Q=0 at t=0
            const float ldt = dtc * lam;
            const float ee  = __expf(-ldt);
            const float a11 = ee * (ldt + 1.f);
            const float a12 = ee * dtc;
            const float a21 = -ee * lam * ldt;
            const float a22 = ee * (1.f - ldt);
            // Q = P0 - A P0 A^T  (P0 = diag(v0, v1))
            const float q00 = v0 - (a11 * a11 * v0 + a12 * a12 * v1);
            const float q01 = -(a11 * a21 * v0 + a12 * a22 * v1);
            const float q11 = v1 - (a21 * a21 * v0 + a22 * a22 * v1);

            // predict
            const float mp0 = a11 * m0 + a12 * m1;
            const float mp1 = a21 * m0 + a22 * m1;
            const float ap00 = a11 * P00 + a12 * P10;
            const float ap01 = a11 * P01 + a12 * P11;
            const float ap10 = a21 * P00 + a22 * P10;
            const float ap11 = a21 * P01 + a22 * P11;
            const float pp00 = ap00 * a11 + ap01 * a12 + q00;
            const float pp01 = ap00 * a21 + ap01 * a22 + q01;
            const float pp10 = ap10 * a11 + ap11 * a12 + q01;
            const float pp11 = ap10 * a21 + ap11 * a22 + q11;

            // update (H = [1,0])
            const float ssv  = pp00 + rb[j];
            const float d    = yb[j] - mp0;
            const float sinv = __builtin_amdgcn_rcpf(ssv + JIT);
            const float W0 = pp00 * sinv;
            const float W1 = pp01 * sinv;
            m0 = mp0 + W0 * d;
            m1 = mp1 + W1 * d;
            P00 = pp00 - W0 * pp00;
            P01 = pp01 - W0 * pp01;
            P10 = pp10 - W1 * pp00;
            P11 = pp11 - W1 * pp01;

            if (tt >= s) {   // uniform across group (s ≡ 0 mod BATCH)
                acc += -0.5f * (d * d * __builtin_amdgcn_rcpf(ssv)
                                + __logf(ssv) + C_LOG2PI);
                mo[tt] = make_float2(m0, m1);
                Po[tt] = make_float4(P00, P01, P10, P11);
            }
        }
    }

    // reduce log_p over the 16 l-lanes sharing this v, then one atomic
    for (int mask = 8; mask >= 1; mask >>= 1)
        acc += __shfl_xor(acc, mask, 16);
    if ((threadIdx.x & 15) == 0)
        atomicAdd(&slp[v], acc);
}

// ---------------------------------------------------------------------------
// Backward RTS smoother, chunked with warm-up from the right. Carry starts
// from the filtered state at t0 (EXACT at t0 == T-1: dt_s[T-1]=0 => A=I,
// Q=0 => smoothed == filtered there per reference). 8-step load batching.
// ---------------------------------------------------------------------------
__global__ __launch_bounds__(256) void kf_bwd(
    const float* __restrict__ dt,
    const float* __restrict__ ls,
    const float* __restrict__ var,
    const float* __restrict__ m_fs,
    const float* __restrict__ P_fs,
    float* __restrict__ mZ,   // (V,L,T)
    float* __restrict__ PZ)   // (V,L,T)
{
    const int tid   = blockIdx.x * 256 + threadIdx.x;
    const int chain = tid & (NCHAIN - 1);
    const int chunk = tid / NCHAIN;
    const int v = chain >> 4;
    const int l = chain & 15;

    const float lam = 1.7320508075688772f / ls[l];
    const float v0  = var[l];
    const float v1  = v0 * lam * lam;

    const int s = chunk * CHUNK;
    const int e = s + CHUNK;
    int t0 = e - 1 + WARM;
    if (t0 > TT - 1) t0 = TT - 1;

    const float* dtv = dt + (size_t)v * (TT - 1);
    const float2* mi = (const float2*)(m_fs + (size_t)chain * TT * 2);
    const float4* Pi = (const float4*)(P_fs + (size_t)chain * TT * 4);
    float* mo = mZ + (size_t)chain * TT;
    float* Po = PZ + (size_t)chain * TT;

    float2 mf2 = mi[t0];
    float4 Pf4 = Pi[t0];
    float ms0 = mf2.x, ms1 = mf2.y;
    float Ps00 = Pf4.x, Ps01 = Pf4.y, Ps10 = Pf4.z, Ps11 = Pf4.w;
    if (t0 < e) { mo[t0] = ms0; Po[t0] = Ps00; }   // only last chunk (t0==T-1)

    // one smoother step at time t (loads given as args)
    auto step = [&](int t, float dtc, float mf0, float mf1,
                    float Pf00, float Pf01, float Pf10, float Pf11) {
        const float ldt = dtc * lam;
        const float ee  = __expf(-ldt);
        const float a11 = ee * (ldt + 1.f);
        const float a12 = ee * dtc;
        const float a21 = -ee * lam * ldt;
        const float a22 = ee * (1.f - ldt);
        const float q00 = v0 - (a11 * a11 * v0 + a12 * a12 * v1);
        const float q01 = -(a11 * a21 * v0 + a12 * a22 * v1);
        const float q11 = v1 - (a21 * a21 * v0 + a22 * a22 * v1);

        const float mp0 = a11 * mf0 + a12 * mf1;
        const float mp1 = a21 * mf0 + a22 * mf1;
        const float ap00 = a11 * Pf00 + a12 * Pf10;   // A_Pf = A @ P_f
        const float ap01 = a11 * Pf01 + a12 * Pf11;
        const float ap10 = a21 * Pf00 + a22 * Pf10;
        const float ap11 = a21 * Pf01 + a22 * Pf11;
        const float pp00 = ap00 * a11 + ap01 * a12 + q00;
        const float pp01 = ap00 * a21 + ap01 * a22 + q01;
        const float pp10 = ap10 * a11 + ap11 * a12 + q01;
        const float pp11 = ap10 * a21 + ap11 * a22 + q11;

        // G = (solve(P_p + jI, A_Pf))^T via 2x2 adjugate
        const float M00 = pp00 + JIT, M01 = pp01, M10 = pp10, M11 = pp11 + JIT;
        const float dinv = __builtin_amdgcn_rcpf(M00 * M11 - M01 * M10);
        const float G00 = (M11 * ap00 - M01 * ap10) * dinv;
        const float G01 = (-M10 * ap00 + M00 * ap10) * dinv;
        const float G10 = (M11 * ap01 - M01 * ap11) * dinv;
        const float G11 = (-M10 * ap01 + M00 * ap11) * dinv;

        const float dm0 = ms0 - mp0, dm1 = ms1 - mp1;
        const float nms0 = mf0 + G00 * dm0 + G01 * dm1;
        const float nms1 = mf1 + G10 * dm0 + G11 * dm1;
        const float D00 = Ps00 - pp00, D01 = Ps01 - pp01;
        const float D10 = Ps10 - pp10, D11 = Ps11 - pp11;
        const float gd00 = G00 * D00 + G01 * D10;
        const float gd01 = G00 * D01 + G01 * D11;
        const float gd10 = G10 * D00 + G11 * D10;
        const float gd11 = G10 * D01 + G11 * D11;
        ms0 = nms0; ms1 = nms1;
        Ps00 = Pf00 - (gd00 * G00 + gd01 * G01);
        Ps01 = Pf01 - (gd00 * G10 + gd01 * G11);
        Ps10 = Pf10 - (gd10 * G00 + gd11 * G01);
        Ps11 = Pf11 - (gd10 * G10 + gd11 * G11);

        if (t < e) { mo[t] = ms0; Po[t] = Ps00; }
    };

    int t = t0 - 1;
    // peel until remaining count (t - s + 1) is a multiple of BATCH
    while (t >= s && ((t + 1) & (BATCH - 1)) != 0) {
        const float dtc = dtv[t];
        mf2 = mi[t]; Pf4 = Pi[t];
        step(t, dtc, mf2.x, mf2.y, Pf4.x, Pf4.y, Pf4.z, Pf4.w);
        --t;
    }
    for (; t >= s; t -= BATCH) {
        float2 mb[BATCH];
        float4 Pb[BATCH];
        float  db[BATCH];
#pragma unroll
        for (int j = 0; j < BATCH; ++j) {
            const int tt = t - j;
            mb[j] = mi[tt];
            Pb[j] = Pi[tt];
            db[j] = dtv[tt];
        }
#pragma unroll
        for (int j = 0; j < BATCH; ++j) {
            const int tt = t - j;
            step(tt, db[j], mb[j].x, mb[j].y, Pb[j].x, Pb[j].y, Pb[j].z, Pb[j].w);
        }
    }
}

extern "C" void kernel_launch(void* const* d_in, const int* in_sizes, int n_in,
                              void* d_out, int out_size, void* d_ws, size_t ws_size,
                              hipStream_t stream) {
    const float* dt  = (const float*)d_in[0];
    const float* y   = (const float*)d_in[1];
    const float* rv  = (const float*)d_in[2];
    const float* ls  = (const float*)d_in[3];
    const float* var = (const float*)d_in[4];

    float* out  = (float*)d_out;
    float* m_fs = out;                                    // V*L*T*2
    float* P_fs = m_fs + (size_t)NCHAIN * TT * 2;         // V*L*T*4
    float* mZ   = P_fs + (size_t)NCHAIN * TT * 4;         // V*L*T
    float* PZ   = mZ + (size_t)NCHAIN * TT;               // V*L*T
    float* slp  = PZ + (size_t)NCHAIN * TT;               // V

    hipMemsetAsync(slp, 0, TV * sizeof(float), stream);   // graph-capture safe

    const int ntask = NCHAIN * NCHUNK;                    // 131072 threads
    kf_fwd<<<ntask / 256, 256, 0, stream>>>(dt, y, rv, ls, var, m_fs, P_fs, slp);
    kf_bwd<<<ntask / 256, 256, 0, stream>>>(dt, ls, var, m_fs, P_fs, mZ, PZ);
}

// Round 3
// 331.110 us; speedup vs baseline: 1.1995x; 1.1826x over previous
//
#include <hip/hip_runtime.h>

#define TV 32
#define TT 8192
#define TL 16
#define NCHAIN (TV * TL)        // 512 chains
#define CHUNK 32
#define WARM 96
#define NCHUNK (TT / CHUNK)     // 256
#define BATCH 16
#define JIT 1e-6f
#define C_LOG2PI 1.837877066409345483560659472811f

// ---------------------------------------------------------------------------
// Forward Kalman filter, chunked with warm-up from the stationary prior.
// __launch_bounds__(256,2): grid gives only ~2 waves/SIMD, so allow up to
// 256 VGPR so the 48 batched loads are truly hoisted (MLP).
// P kept symmetric (P00,P01,P11). m stored as float4 every 2 steps.
// ---------------------------------------------------------------------------
__global__ __launch_bounds__(256, 2) void kf_fwd(
    const float* __restrict__ dt,    // (V, T-1)
    const float* __restrict__ y,     // (V, T, L)
    const float* __restrict__ rvar,  // (V, T, L)
    const float* __restrict__ ls,    // (L)
    const float* __restrict__ var,   // (L)
    float* __restrict__ m_fs,        // (V,L,T,2)
    float* __restrict__ P_fs,        // (V,L,T,4)
    float* __restrict__ slp)         // (V) -- pre-zeroed, atomicAdd
{
    const int tid   = blockIdx.x * 256 + threadIdx.x;
    const int chain = tid & (NCHAIN - 1);
    const int chunk = tid / NCHAIN;
    const int v = chain >> 4;
    const int l = chain & 15;

    const float lam = 1.7320508075688772f / ls[l];
    const float v0  = var[l];
    const float v1  = v0 * lam * lam;

    const int s  = chunk * CHUNK;
    const int e  = s + CHUNK;
    const int u0 = (s >= WARM) ? (s - WARM) : 0;   // multiple of 32

    const float* dtv = dt + (size_t)v * (TT - 1);
    const float* yp  = y    + (size_t)v * TT * TL + l;
    const float* rp  = rvar + (size_t)v * TT * TL + l;
    float4* mo4 = (float4*)(m_fs + (size_t)chain * TT * 2);  // [t>>1]
    float4* Po  = (float4*)(P_fs + (size_t)chain * TT * 4);

    float m0 = 0.f, m1 = 0.f;
    float P00 = v0, P01 = 0.f, P11 = v1;
    float acc = 0.f;
    float bm0 = 0.f, bm1 = 0.f;

    for (int t = u0; t < e; t += BATCH) {
        float yb[BATCH], rb[BATCH], db[BATCH];
#pragma unroll
        for (int j = 0; j < BATCH; ++j) {
            const int tt = t + j;
            yb[j] = yp[(size_t)tt * TL];
            rb[j] = rp[(size_t)tt * TL];
            db[j] = dtv[(tt >= 1) ? (tt - 1) : 0];
        }
#pragma unroll
        for (int j = 0; j < BATCH; ++j) {
            const int tt = t + j;
            const float dtc = (tt == 0) ? 0.f : db[j];   // exact A=I,Q=0 at t=0
            const float ldt = dtc * lam;
            const float ee  = __expf(-ldt);
            const float a11 = ee * (ldt + 1.f);
            const float a12 = ee * dtc;
            const float a21 = -ee * lam * ldt;
            const float a22 = ee * (1.f - ldt);
            const float q00 = v0 - (a11 * a11 * v0 + a12 * a12 * v1);
            const float q01 = -(a11 * a21 * v0 + a12 * a22 * v1);
            const float q11 = v1 - (a21 * a21 * v0 + a22 * a22 * v1);

            // predict (P symmetric)
            const float mp0 = a11 * m0 + a12 * m1;
            const float mp1 = a21 * m0 + a22 * m1;
            const float ap00 = a11 * P00 + a12 * P01;
            const float ap01 = a11 * P01 + a12 * P11;
            const float ap10 = a21 * P00 + a22 * P01;
            const float ap11 = a21 * P01 + a22 * P11;
            const float pp00 = ap00 * a11 + ap01 * a12 + q00;
            const float pp01 = ap00 * a21 + ap01 * a22 + q01;
            const float pp11 = ap10 * a21 + ap11 * a22 + q11;

            // update (H = [1,0])
            const float ssv  = pp00 + rb[j];
            const float d    = yb[j] - mp0;
            const float sinv = __builtin_amdgcn_rcpf(ssv + JIT);
            const float W0 = pp00 * sinv;
            const float W1 = pp01 * sinv;
            m0 = mp0 + W0 * d;
            m1 = mp1 + W1 * d;
            P00 = pp00 - W0 * pp00;
            P01 = pp01 - W0 * pp01;
            P11 = pp11 - W1 * pp01;

            if (tt >= s) {   // batch-uniform (s, u0, e multiples of 32)
                acc += -0.5f * (d * d * __builtin_amdgcn_rcpf(ssv)
                                + __logf(ssv) + C_LOG2PI);
                if ((j & 1) == 0) { bm0 = m0; bm1 = m1; }        // tt even
                else mo4[tt >> 1] = make_float4(bm0, bm1, m0, m1);
                Po[tt] = make_float4(P00, P01, P01, P11);
            }
        }
    }

    for (int mask = 8; mask >= 1; mask >>= 1)
        acc += __shfl_xor(acc, mask, 16);
    if ((threadIdx.x & 15) == 0)
        atomicAdd(&slp[v], acc);
}

// ---------------------------------------------------------------------------
// Backward RTS smoother, chunked with warm-up from the right (carry exact
// at t0==T-1). Batched loads (16 steps in flight); outputs buffered 4 steps
// and stored as float4 to kill partial-line write amplification.
// ---------------------------------------------------------------------------
__global__ __launch_bounds__(256, 2) void kf_bwd(
    const float* __restrict__ dt,
    const float* __restrict__ ls,
    const float* __restrict__ var,
    const float* __restrict__ m_fs,
    const float* __restrict__ P_fs,
    float* __restrict__ mZ,   // (V,L,T)
    float* __restrict__ PZ)   // (V,L,T)
{
    const int tid   = blockIdx.x * 256 + threadIdx.x;
    const int chain = tid & (NCHAIN - 1);
    const int chunk = tid / NCHAIN;
    const int v = chain >> 4;
    const int l = chain & 15;

    const float lam = 1.7320508075688772f / ls[l];
    const float v0  = var[l];
    const float v1  = v0 * lam * lam;

    const int s = chunk * CHUNK;
    const int e = s + CHUNK;
    int t0 = e - 1 + WARM;
    if (t0 > TT - 1) t0 = TT - 1;

    const float* dtv = dt + (size_t)v * (TT - 1);
    const float2* mi = (const float2*)(m_fs + (size_t)chain * TT * 2);
    const float4* Pi = (const float4*)(P_fs + (size_t)chain * TT * 4);
    float* mo = mZ + (size_t)chain * TT;
    float* Po = PZ + (size_t)chain * TT;

    float2 mf2 = mi[t0];
    float4 Pf4 = Pi[t0];
    float ms0 = mf2.x, ms1 = mf2.y;
    float Ps00 = Pf4.x, Ps01 = Pf4.y, Ps11 = Pf4.w;
    if (t0 < e) { mo[t0] = ms0; Po[t0] = Ps00; }   // only when t0==e-1 (exact)

    // one smoother step; updates carry (ms*, Ps*)
    auto step = [&](float dtc, float mf0, float mf1,
                    float Pf00, float Pf01, float Pf11) {
        const float ldt = dtc * lam;
        const float ee  = __expf(-ldt);
        const float a11 = ee * (ldt + 1.f);
        const float a12 = ee * dtc;
        const float a21 = -ee * lam * ldt;
        const float a22 = ee * (1.f - ldt);
        const float q00 = v0 - (a11 * a11 * v0 + a12 * a12 * v1);
        const float q01 = -(a11 * a21 * v0 + a12 * a22 * v1);
        const float q11 = v1 - (a21 * a21 * v0 + a22 * a22 * v1);

        const float mp0 = a11 * mf0 + a12 * mf1;
        const float mp1 = a21 * mf0 + a22 * mf1;
        const float ap00 = a11 * Pf00 + a12 * Pf01;   // A @ P_f (P_f symmetric)
        const float ap01 = a11 * Pf01 + a12 * Pf11;
        const float ap10 = a21 * Pf00 + a22 * Pf01;
        const float ap11 = a21 * Pf01 + a22 * Pf11;
        const float pp00 = ap00 * a11 + ap01 * a12 + q00;
        const float pp01 = ap00 * a21 + ap01 * a22 + q01;
        const float pp11 = ap10 * a21 + ap11 * a22 + q11;

        // G = (solve(P_p + jI, A_Pf))^T via 2x2 adjugate
        const float M00 = pp00 + JIT, M11 = pp11 + JIT;
        const float dinv = __builtin_amdgcn_rcpf(M00 * M11 - pp01 * pp01);
        const float G00 = (M11 * ap00 - pp01 * ap10) * dinv;
        const float G01 = (-pp01 * ap00 + M00 * ap10) * dinv;
        const float G10 = (M11 * ap01 - pp01 * ap11) * dinv;
        const float G11 = (-pp01 * ap01 + M00 * ap11) * dinv;

        const float dm0 = ms0 - mp0, dm1 = ms1 - mp1;
        const float nms0 = mf0 + G00 * dm0 + G01 * dm1;
        const float nms1 = mf1 + G10 * dm0 + G11 * dm1;
        const float D00 = Ps00 - pp00, D01 = Ps01 - pp01, D11 = Ps11 - pp11;
        const float gd00 = G00 * D00 + G01 * D01;
        const float gd01 = G00 * D01 + G01 * D11;
        const float gd10 = G10 * D00 + G11 * D01;
        const float gd11 = G10 * D01 + G11 * D11;
        ms0 = nms0; ms1 = nms1;
        Ps00 = Pf00 - (gd00 * G00 + gd01 * G01);
        Ps01 = Pf01 - (gd00 * G10 + gd01 * G11);
        Ps11 = Pf11 - (gd10 * G10 + gd11 * G11);
    };

    int t = t0 - 1;
    // peel until t ≡ 15 (mod 16); scalar stores (rare: only tail chunks)
    for (; t >= s && (t & 15) != 15; --t) {
        mf2 = mi[t]; Pf4 = Pi[t];
        step(dtv[t], mf2.x, mf2.y, Pf4.x, Pf4.y, Pf4.w);
        if (t < e) { mo[t] = ms0; Po[t] = Ps00; }
    }

    float b0m = 0.f, b1m = 0.f, b2m = 0.f, b3m = 0.f;
    float b0P = 0.f, b1P = 0.f, b2P = 0.f, b3P = 0.f;

    for (; t >= s; t -= BATCH) {
        float2 mb[BATCH];
        float4 Pb[BATCH];
        float  db[BATCH];
#pragma unroll
        for (int j = 0; j < BATCH; ++j) {
            const int tt = t - j;
            mb[j] = mi[tt];
            Pb[j] = Pi[tt];
            db[j] = dtv[tt];
        }
        const bool wr = (t < e);   // whole 16-block uniform (e mult of 32)
#pragma unroll
        for (int j = 0; j < BATCH; ++j) {
            step(db[j], mb[j].x, mb[j].y, Pb[j].x, Pb[j].y, Pb[j].w);
            const int slot = 3 - (j & 3);       // t-j: &3 = 3,2,1,0 repeating
            if (slot == 3)      { b3m = ms0; b3P = Ps00; }
            else if (slot == 2) { b2m = ms0; b2P = Ps00; }
            else if (slot == 1) { b1m = ms0; b1P = Ps00; }
            else {
                b0m = ms0; b0P = Ps00;
                if (wr) {
                    const int tt = t - j;       // tt & 3 == 0, 16B-aligned
                    *(float4*)(mo + tt) = make_float4(b0m, b1m, b2m, b3m);
                    *(float4*)(Po + tt) = make_float4(b0P, b1P, b2P, b3P);
                }
            }
        }
    }
}

extern "C" void kernel_launch(void* const* d_in, const int* in_sizes, int n_in,
                              void* d_out, int out_size, void* d_ws, size_t ws_size,
                              hipStream_t stream) {
    const float* dt  = (const float*)d_in[0];
    const float* y   = (const float*)d_in[1];
    const float* rv  = (const float*)d_in[2];
    const float* ls  = (const float*)d_in[3];
    const float* var = (const float*)d_in[4];

    float* out  = (float*)d_out;
    float* m_fs = out;                                    // V*L*T*2
    float* P_fs = m_fs + (size_t)NCHAIN * TT * 2;         // V*L*T*4
    float* mZ   = P_fs + (size_t)NCHAIN * TT * 4;         // V*L*T
    float* PZ   = mZ + (size_t)NCHAIN * TT;               // V*L*T
    float* slp  = PZ + (size_t)NCHAIN * TT;               // V

    hipMemsetAsync(slp, 0, TV * sizeof(float), stream);   // graph-capture safe

    const int ntask = NCHAIN * NCHUNK;                    // 131072 threads
    kf_fwd<<<ntask / 256, 256, 0, stream>>>(dt, y, rv, ls, var, m_fs, P_fs, slp);
    kf_bwd<<<ntask / 256, 256, 0, stream>>>(dt, ls, var, m_fs, P_fs, mZ, PZ);
}